// Round 6
// baseline (44.175 us; speedup 1.0000x reference)
//
#include <hip/hip_runtime.h>

// ScaledRBFKernel: out[i][j] = outputscale * exp(-2 * ||x1[i] - x2[j]||^2)
// x1: [8192,2] f32, x2: [8192,2] f32, out: [8192,8192] f32 (256 MiB -> write-BW bound)
// LENGTHSCALE = 0.5 -> 1/(2*l^2) = 2.0 (baked in)
// R6: multi-row persistent-ish blocks. Each block owns one column tile
// (c4 and c4+1024) and walks ROWS_PER_BLOCK=8 consecutive rows; the x2
// fragment is row-invariant and stays in registers. Inner loop: 1 broadcast
// x1 load, 8 exps, 2 dense global_store_dwordx4 (1 KB/wave each).
// History: R3 nt-stores -2.5x (L2 write-combining bypass); R4 strided
// store pairs +14us (50% burst density); R5 dense 2-tile = R1 = 44 us.

#define N_ROWS 8192
#define M_COLS 8192
#define ROWS_PER_BLOCK 8

typedef float f32x4 __attribute__((ext_vector_type(4)));

__global__ __launch_bounds__(256) void ScaledRBFKernel_55052890800187_kernel(
    const float2* __restrict__ x1,   // [N,2] as float2
    const float2* __restrict__ x2,   // [M,2] as float2
    const float* __restrict__ oscale,
    float* __restrict__ out)
{
    const int c4 = blockIdx.x * blockDim.x + threadIdx.x;  // float4-col 0..1023 (tile A)
    const int i0 = blockIdx.y * ROWS_PER_BLOCK;            // first row of this block

    const float s = oscale[0];

    // Row-invariant x2 fragments: 8 points, 16 VGPRs, loaded ONCE per block.
    const f32x4* x2v = reinterpret_cast<const f32x4*>(x2);  // 2 points per f32x4
    const f32x4 pa0 = x2v[c4 * 2 + 0];
    const f32x4 pa1 = x2v[c4 * 2 + 1];
    const f32x4 pb0 = x2v[(c4 + 1024) * 2 + 0];
    const f32x4 pb1 = x2v[(c4 + 1024) * 2 + 1];

    f32x4* orow = reinterpret_cast<f32x4*>(out) + (size_t)i0 * (M_COLS / 4);

#pragma unroll
    for (int r = 0; r < ROWS_PER_BLOCK; ++r) {
        const float2 a = x1[i0 + r];   // wave-broadcast load (L1 hit)

        f32x4 ra, rb;
        {
            float dx = a.x - pa0.x, dy = a.y - pa0.y;
            ra.x = s * __expf(-2.0f * (dx * dx + dy * dy));
        }
        {
            float dx = a.x - pa0.z, dy = a.y - pa0.w;
            ra.y = s * __expf(-2.0f * (dx * dx + dy * dy));
        }
        {
            float dx = a.x - pa1.x, dy = a.y - pa1.y;
            ra.z = s * __expf(-2.0f * (dx * dx + dy * dy));
        }
        {
            float dx = a.x - pa1.z, dy = a.y - pa1.w;
            ra.w = s * __expf(-2.0f * (dx * dx + dy * dy));
        }
        {
            float dx = a.x - pb0.x, dy = a.y - pb0.y;
            rb.x = s * __expf(-2.0f * (dx * dx + dy * dy));
        }
        {
            float dx = a.x - pb0.z, dy = a.y - pb0.w;
            rb.y = s * __expf(-2.0f * (dx * dx + dy * dy));
        }
        {
            float dx = a.x - pb1.x, dy = a.y - pb1.y;
            rb.z = s * __expf(-2.0f * (dx * dx + dy * dy));
        }
        {
            float dx = a.x - pb1.z, dy = a.y - pb1.w;
            rb.w = s * __expf(-2.0f * (dx * dx + dy * dy));
        }

        orow[c4]        = ra;   // dense 16 B/lane, contiguous across wave
        orow[c4 + 1024] = rb;   // dense second tile
        orow += M_COLS / 4;     // next row
    }
}

extern "C" void kernel_launch(void* const* d_in, const int* in_sizes, int n_in,
                              void* d_out, int out_size, void* d_ws, size_t ws_size,
                              hipStream_t stream)
{
    const float2* x1 = (const float2*)d_in[0];
    const float2* x2 = (const float2*)d_in[1];
    const float*  os = (const float*)d_in[2];
    float* out = (float*)d_out;

    // x: 1024 float4-cols (tile A) / 256 threads -> 4 blocks;
    // y: 8192 / 8 rows-per-block -> 1024. 4096 blocks, 64 KB output each.
    dim3 block(256, 1, 1);
    dim3 grid(1024 / 256, N_ROWS / ROWS_PER_BLOCK, 1);
    ScaledRBFKernel_55052890800187_kernel<<<grid, block, 0, stream>>>(x1, x2, os, out);
}